// Round 4
// baseline (3013.276 us; speedup 1.0000x reference)
//
#include <hip/hip_runtime.h>

#define N_NODES 100000
#define N_EDGES 1600000
#define DIN 128
#define DOUT 128
#define N_SUP 2
#define E_TOT (N_SUP * N_EDGES)          // 3,200,000

#define BIN_ROWS 128
#define BSHIFT 7
#define NBINS ((N_NODES + BIN_ROWS - 1) / BIN_ROWS)    // 782

#define SC_EPT 16
#define SC_BLOCK 256
#define SC_CHUNK (SC_EPT * SC_BLOCK)                    // 4096
#define NBLK_SC ((E_TOT + SC_CHUNK - 1) / SC_CHUNK)     // 782

typedef float        f32x4 __attribute__((ext_vector_type(4)));
typedef unsigned int u32;
typedef u32          u32x4 __attribute__((ext_vector_type(4)));

// round-to-nearest-even fp32 -> bf16 pair packed in one u32 (lo = even feat)
static __device__ __forceinline__ u32 pack_bf16x2(float lo, float hi) {
    u32 ul = __float_as_uint(lo);
    u32 uh = __float_as_uint(hi);
    ul = (ul + 0x7FFFu + ((ul >> 16) & 1u)) >> 16;
    uh = ((uh + 0x7FFFu + ((uh >> 16) & 1u)) >> 16) << 16;
    return ul | uh;
}

// ---------------------------------------------------------------------------
// GEMM: pre[s] = x @ w[s], fp32 vector ALU, 8x8/thread tile, bf16 output.
// pre layout: u32[node][64] where u32 j holds features 2j (lo), 2j+1 (hi).
// ---------------------------------------------------------------------------
__global__ __launch_bounds__(256) void gemm_kernel(const float* __restrict__ x,
                                                   const float* __restrict__ w,
                                                   u32* __restrict__ pre) {
    __shared__ float xT[DIN][128];   // [k][row], 64 KB
    const int s = blockIdx.y;
    const int row0 = blockIdx.x * 128;
    const int t = threadIdx.x;

    {
        const int r = t >> 1;
        const int kh = (t & 1) * 64;
        const int gr = row0 + r;
        const float* xp = x + (size_t)gr * DIN + kh;
        #pragma unroll
        for (int kk = 0; kk < 64; kk += 4) {
            f32x4 v = {0.f, 0.f, 0.f, 0.f};
            if (gr < N_NODES) v = __builtin_nontemporal_load((const f32x4*)(xp + kk));
            xT[kh + kk + 0][r] = v.x;
            xT[kh + kk + 1][r] = v.y;
            xT[kh + kk + 2][r] = v.z;
            xT[kh + kk + 3][r] = v.w;
        }
    }
    __syncthreads();

    const int tx = t & 15;
    const int ty = t >> 4;
    const float* wp = w + (size_t)s * DIN * DOUT + tx * 8;

    float acc[8][8];
    #pragma unroll
    for (int i = 0; i < 8; i++)
        #pragma unroll
        for (int j = 0; j < 8; j++) acc[i][j] = 0.f;

    #pragma unroll 2
    for (int k = 0; k < DIN; k++) {
        const float4 xa = *(const float4*)&xT[k][ty * 8];
        const float4 xb = *(const float4*)&xT[k][ty * 8 + 4];
        const float4 wa = *(const float4*)(wp + (size_t)k * DOUT);
        const float4 wb = *(const float4*)(wp + (size_t)k * DOUT + 4);
        const float xv[8] = {xa.x, xa.y, xa.z, xa.w, xb.x, xb.y, xb.z, xb.w};
        const float wv[8] = {wa.x, wa.y, wa.z, wa.w, wb.x, wb.y, wb.z, wb.w};
        #pragma unroll
        for (int i = 0; i < 8; i++)
            #pragma unroll
            for (int j = 0; j < 8; j++)
                acc[i][j] += xv[i] * wv[j];
    }

    #pragma unroll
    for (int i = 0; i < 8; i++) {
        const int gr = row0 + ty * 8 + i;
        if (gr < N_NODES) {
            u32* op = pre + ((size_t)s * N_NODES + gr) * 64 + tx * 4;
            u32x4 pk;
            pk.x = pack_bf16x2(acc[i][0], acc[i][1]);
            pk.y = pack_bf16x2(acc[i][2], acc[i][3]);
            pk.z = pack_bf16x2(acc[i][4], acc[i][5]);
            pk.w = pack_bf16x2(acc[i][6], acc[i][7]);
            __builtin_nontemporal_store(pk, (u32x4*)op);
        }
    }
}

// ---------------------------------------------------------------------------
// Bin histogram: LDS hist per block, one global atomic per (block, bin)
// ---------------------------------------------------------------------------
__global__ __launch_bounds__(256) void binhist_kernel(const int* __restrict__ rows,
                                                      int* __restrict__ bin_cnt) {
    __shared__ int h[NBINS];
    const int t = threadIdx.x;
    for (int i = t; i < NBINS; i += 256) h[i] = 0;
    __syncthreads();
    const int base = blockIdx.x * SC_CHUNK;
    #pragma unroll
    for (int j = 0; j < SC_EPT; j++) {
        const int i = base + j * 256 + t;
        if (i < E_TOT) atomicAdd(&h[__builtin_nontemporal_load(rows + i) >> BSHIFT], 1);
    }
    __syncthreads();
    for (int i = t; i < NBINS; i += 256)
        if (h[i]) atomicAdd(&bin_cnt[i], h[i]);
}

// ---------------------------------------------------------------------------
// Exclusive scan over NBINS (single block)
// ---------------------------------------------------------------------------
__global__ __launch_bounds__(1024) void binscan_kernel(const int* __restrict__ bin_cnt,
                                                       int* __restrict__ bin_base,
                                                       int* __restrict__ bin_cursor) {
    __shared__ int s[1024];
    const int t = threadIdx.x;
    const int v = (t < NBINS) ? bin_cnt[t] : 0;
    s[t] = v;
    __syncthreads();
    #pragma unroll
    for (int off = 1; off < 1024; off <<= 1) {
        const int u = (t >= off) ? s[t - off] : 0;
        __syncthreads();
        s[t] += u;
        __syncthreads();
    }
    if (t < NBINS) {
        const int ex = s[t] - v;
        bin_base[t] = ex;
        bin_cursor[t] = ex;
    }
    if (t == 0) bin_base[NBINS] = E_TOT;
}

// ---------------------------------------------------------------------------
// Binned scatter: per-block LDS bin counts, one global run reservation per
// (block,bin), then stores at run_base + local_pos. A run's stores all come
// from one block -> one XCD -> lines assemble in that L2 (kills the 64B/edge
// write-back amplification seen in rounds 2-3).
// payload.x = col_eff (18b) | row_low (7b) << 18 ; payload.y = val bits
// ---------------------------------------------------------------------------
__global__ __launch_bounds__(256) void binscatter_kernel(const int* __restrict__ rows,
                                                         const int* __restrict__ cols,
                                                         const float* __restrict__ vals,
                                                         int* __restrict__ bin_cursor,
                                                         uint2* __restrict__ edata) {
    __shared__ int lcnt[NBINS];
    __shared__ int lbase[NBINS];
    const int t = threadIdx.x;
    for (int i = t; i < NBINS; i += 256) lcnt[i] = 0;
    __syncthreads();

    const int base = blockIdx.x * SC_CHUNK;
    int bin[SC_EPT], lpos[SC_EPT];
    uint2 pay[SC_EPT];
    #pragma unroll
    for (int j = 0; j < SC_EPT; j++) {
        const int i = base + j * 256 + t;
        if (i < E_TOT) {
            const int r = __builtin_nontemporal_load(rows + i);
            const int c = __builtin_nontemporal_load(cols + i);
            const float v = __builtin_nontemporal_load(vals + i);
            const int b = r >> BSHIFT;
            bin[j] = b;
            lpos[j] = atomicAdd(&lcnt[b], 1);
            pay[j].x = (u32)(c + ((i >= N_EDGES) ? N_NODES : 0)) |
                       ((u32)(r & (BIN_ROWS - 1)) << 18);
            pay[j].y = __float_as_uint(v);
        } else {
            bin[j] = -1;
        }
    }
    __syncthreads();
    for (int b = t; b < NBINS; b += 256) {
        const int c = lcnt[b];
        if (c) lbase[b] = atomicAdd(&bin_cursor[b], c);
    }
    __syncthreads();
    #pragma unroll
    for (int j = 0; j < SC_EPT; j++) {
        if (bin[j] >= 0) edata[lbase[bin[j]] + lpos[j]] = pay[j];
    }
}

// ---------------------------------------------------------------------------
// Bin gather: one block per 128-row bin. 64 KB fp32 LDS tile, edges
// accumulated via LDS atomicAdd (ds_add_f32). Lane l owns feature pair
// (2l, 2l+1). Fused bias + ReLU epilogue, coalesced NT store.
// ---------------------------------------------------------------------------
__global__ __launch_bounds__(256) void bingather_kernel(const u32* __restrict__ pre,
                                                        const uint2* __restrict__ edata,
                                                        const int* __restrict__ bin_base,
                                                        const float* __restrict__ bias,
                                                        float* __restrict__ out) {
    __shared__ float tile[BIN_ROWS][DOUT];   // 64 KB
    const int t = threadIdx.x;
    const int lane = t & 63;
    const int w = t >> 6;

    for (int i = t; i < BIN_ROWS * DOUT / 4; i += 256)
        ((f32x4*)tile)[i] = (f32x4){0.f, 0.f, 0.f, 0.f};
    __syncthreads();

    const int b = blockIdx.x;
    const int beg = bin_base[b];
    const int end = bin_base[b + 1];

    int e = beg + w * 4;
    for (; e + 3 < end; e += 16) {
        const uint2 d0 = edata[e];
        const uint2 d1 = edata[e + 1];
        const uint2 d2 = edata[e + 2];
        const uint2 d3 = edata[e + 3];
        const u32 u0 = pre[(size_t)(d0.x & 0x3FFFFu) * 64 + lane];
        const u32 u1 = pre[(size_t)(d1.x & 0x3FFFFu) * 64 + lane];
        const u32 u2 = pre[(size_t)(d2.x & 0x3FFFFu) * 64 + lane];
        const u32 u3 = pre[(size_t)(d3.x & 0x3FFFFu) * 64 + lane];
        const float v0 = __uint_as_float(d0.y);
        const float v1 = __uint_as_float(d1.y);
        const float v2 = __uint_as_float(d2.y);
        const float v3 = __uint_as_float(d3.y);
        atomicAdd(&tile[d0.x >> 18][lane * 2],     v0 * __uint_as_float(u0 << 16));
        atomicAdd(&tile[d0.x >> 18][lane * 2 + 1], v0 * __uint_as_float(u0 & 0xFFFF0000u));
        atomicAdd(&tile[d1.x >> 18][lane * 2],     v1 * __uint_as_float(u1 << 16));
        atomicAdd(&tile[d1.x >> 18][lane * 2 + 1], v1 * __uint_as_float(u1 & 0xFFFF0000u));
        atomicAdd(&tile[d2.x >> 18][lane * 2],     v2 * __uint_as_float(u2 << 16));
        atomicAdd(&tile[d2.x >> 18][lane * 2 + 1], v2 * __uint_as_float(u2 & 0xFFFF0000u));
        atomicAdd(&tile[d3.x >> 18][lane * 2],     v3 * __uint_as_float(u3 << 16));
        atomicAdd(&tile[d3.x >> 18][lane * 2 + 1], v3 * __uint_as_float(u3 & 0xFFFF0000u));
    }
    #pragma unroll
    for (int k = 0; k < 4; k++) {
        const int ee = e + k;
        if (ee < end) {
            const uint2 d = edata[ee];
            const u32 u = pre[(size_t)(d.x & 0x3FFFFu) * 64 + lane];
            const float v = __uint_as_float(d.y);
            atomicAdd(&tile[d.x >> 18][lane * 2],     v * __uint_as_float(u << 16));
            atomicAdd(&tile[d.x >> 18][lane * 2 + 1], v * __uint_as_float(u & 0xFFFF0000u));
        }
    }
    __syncthreads();

    const int row0 = b * BIN_ROWS;
    const int nrows = min(BIN_ROWS, N_NODES - row0);
    for (int i = t; i < nrows * (DOUT / 4); i += 256) {
        const int r = i >> 5;
        const int fq = i & 31;
        const f32x4 a = ((const f32x4*)&tile[r][0])[fq];
        const f32x4 bb = *(const f32x4*)(bias + fq * 4);
        f32x4 o;
        o.x = fmaxf(a.x + bb.x, 0.f);
        o.y = fmaxf(a.y + bb.y, 0.f);
        o.z = fmaxf(a.z + bb.z, 0.f);
        o.w = fmaxf(a.w + bb.w, 0.f);
        __builtin_nontemporal_store(o, (f32x4*)(out + (size_t)(row0 + r) * DOUT + fq * 4));
    }
}

extern "C" void kernel_launch(void* const* d_in, const int* in_sizes, int n_in,
                              void* d_out, int out_size, void* d_ws, size_t ws_size,
                              hipStream_t stream) {
    (void)in_sizes; (void)n_in; (void)out_size; (void)ws_size;
    const float* x        = (const float*)d_in[0];   // [N, 128]
    const float* w        = (const float*)d_in[1];   // [2, 128, 128]
    const float* bias     = (const float*)d_in[2];   // [128]
    const float* sup_vals = (const float*)d_in[3];   // [2, E] flat
    const int*   sup_rows = (const int*)d_in[4];     // [2, E] flat
    const int*   sup_cols = (const int*)d_in[5];     // [2, E] flat
    float* out = (float*)d_out;                      // [N, 128]

    // ws layout
    char* ws = (char*)d_ws;
    u32*   pre       = (u32*)ws;                                     // 2*N*64*4 = 51.2 MB
    uint2* edata     = (uint2*)(ws + (size_t)N_SUP * N_NODES * 64 * 4);  // 25.6 MB
    int*   bin_cnt   = (int*)((char*)edata + (size_t)E_TOT * 8);
    int*   bin_base  = bin_cnt + NBINS;          // NBINS+1
    int*   bin_cursor= bin_base + NBINS + 1;

    // 1. GEMM -> bf16 pre
    {
        dim3 grid((N_NODES + 127) / 128, N_SUP);
        gemm_kernel<<<grid, 256, 0, stream>>>(x, w, pre);
    }
    // 2. bin CSR build
    hipMemsetAsync(bin_cnt, 0, NBINS * sizeof(int), stream);
    binhist_kernel<<<NBLK_SC, 256, 0, stream>>>(sup_rows, bin_cnt);
    binscan_kernel<<<1, 1024, 0, stream>>>(bin_cnt, bin_base, bin_cursor);
    binscatter_kernel<<<NBLK_SC, 256, 0, stream>>>(sup_rows, sup_cols, sup_vals,
                                                   bin_cursor, edata);
    // 3. bin gather + bias + ReLU
    bingather_kernel<<<NBINS, 256, 0, stream>>>(pre, edata, bin_base, bias, out);
}

// Round 6
// 547.853 us; speedup vs baseline: 5.5002x; 5.5002x over previous
//
#include <hip/hip_runtime.h>

#define N_NODES 100000
#define N_EDGES 1600000
#define DIN 128
#define DOUT 128
#define N_SUP 2
#define E_TOT (N_SUP * N_EDGES)          // 3,200,000

#define BIN_ROWS 128
#define BSHIFT 7
#define NBINS ((N_NODES + BIN_ROWS - 1) / BIN_ROWS)    // 782

#define SC_EPT 16
#define SC_BLOCK 256
#define SC_CHUNK (SC_EPT * SC_BLOCK)                    // 4096
#define NBLK_SC ((E_TOT + SC_CHUNK - 1) / SC_CHUNK)     // 782

typedef float        f32x2 __attribute__((ext_vector_type(2)));
typedef float        f32x4 __attribute__((ext_vector_type(4)));
typedef unsigned int u32;
typedef u32          u32x2 __attribute__((ext_vector_type(2)));
typedef u32          u32x4 __attribute__((ext_vector_type(4)));

// round-to-nearest-even fp32 -> bf16 pair packed in one u32 (lo = even feat)
static __device__ __forceinline__ u32 pack_bf16x2(float lo, float hi) {
    u32 ul = __float_as_uint(lo);
    u32 uh = __float_as_uint(hi);
    ul = (ul + 0x7FFFu + ((ul >> 16) & 1u)) >> 16;
    uh = ((uh + 0x7FFFu + ((uh >> 16) & 1u)) >> 16) << 16;
    return ul | uh;
}

// ---------------------------------------------------------------------------
// GEMM: pre[s] = x @ w[s], fp32 vector ALU, 8x8/thread tile, bf16 output.
// pre layout: u32[node][64] where u32 j holds features 2j (lo), 2j+1 (hi).
// ---------------------------------------------------------------------------
__global__ __launch_bounds__(256) void gemm_kernel(const float* __restrict__ x,
                                                   const float* __restrict__ w,
                                                   u32* __restrict__ pre) {
    __shared__ float xT[DIN][128];   // [k][row], 64 KB
    const int s = blockIdx.y;
    const int row0 = blockIdx.x * 128;
    const int t = threadIdx.x;

    {
        const int r = t >> 1;
        const int kh = (t & 1) * 64;
        const int gr = row0 + r;
        const float* xp = x + (size_t)gr * DIN + kh;
        #pragma unroll
        for (int kk = 0; kk < 64; kk += 4) {
            f32x4 v = {0.f, 0.f, 0.f, 0.f};
            if (gr < N_NODES) v = __builtin_nontemporal_load((const f32x4*)(xp + kk));
            xT[kh + kk + 0][r] = v.x;
            xT[kh + kk + 1][r] = v.y;
            xT[kh + kk + 2][r] = v.z;
            xT[kh + kk + 3][r] = v.w;
        }
    }
    __syncthreads();

    const int tx = t & 15;
    const int ty = t >> 4;
    const float* wp = w + (size_t)s * DIN * DOUT + tx * 8;

    float acc[8][8];
    #pragma unroll
    for (int i = 0; i < 8; i++)
        #pragma unroll
        for (int j = 0; j < 8; j++) acc[i][j] = 0.f;

    #pragma unroll 2
    for (int k = 0; k < DIN; k++) {
        const float4 xa = *(const float4*)&xT[k][ty * 8];
        const float4 xb = *(const float4*)&xT[k][ty * 8 + 4];
        const float4 wa = *(const float4*)(wp + (size_t)k * DOUT);
        const float4 wb = *(const float4*)(wp + (size_t)k * DOUT + 4);
        const float xv[8] = {xa.x, xa.y, xa.z, xa.w, xb.x, xb.y, xb.z, xb.w};
        const float wv[8] = {wa.x, wa.y, wa.z, wa.w, wb.x, wb.y, wb.z, wb.w};
        #pragma unroll
        for (int i = 0; i < 8; i++)
            #pragma unroll
            for (int j = 0; j < 8; j++)
                acc[i][j] += xv[i] * wv[j];
    }

    #pragma unroll
    for (int i = 0; i < 8; i++) {
        const int gr = row0 + ty * 8 + i;
        if (gr < N_NODES) {
            u32* op = pre + ((size_t)s * N_NODES + gr) * 64 + tx * 4;
            u32x4 pk;
            pk.x = pack_bf16x2(acc[i][0], acc[i][1]);
            pk.y = pack_bf16x2(acc[i][2], acc[i][3]);
            pk.z = pack_bf16x2(acc[i][4], acc[i][5]);
            pk.w = pack_bf16x2(acc[i][6], acc[i][7]);
            __builtin_nontemporal_store(pk, (u32x4*)op);
        }
    }
}

// ---------------------------------------------------------------------------
// Bin histogram: LDS hist per block, one global atomic per (block, bin)
// ---------------------------------------------------------------------------
__global__ __launch_bounds__(256) void binhist_kernel(const int* __restrict__ rows,
                                                      int* __restrict__ bin_cnt) {
    __shared__ int h[NBINS];
    const int t = threadIdx.x;
    for (int i = t; i < NBINS; i += 256) h[i] = 0;
    __syncthreads();
    const int base = blockIdx.x * SC_CHUNK;
    #pragma unroll
    for (int j = 0; j < SC_EPT; j++) {
        const int i = base + j * 256 + t;
        if (i < E_TOT) atomicAdd(&h[__builtin_nontemporal_load(rows + i) >> BSHIFT], 1);
    }
    __syncthreads();
    for (int i = t; i < NBINS; i += 256)
        if (h[i]) atomicAdd(&bin_cnt[i], h[i]);
}

// ---------------------------------------------------------------------------
// Exclusive scan over NBINS (single block)
// ---------------------------------------------------------------------------
__global__ __launch_bounds__(1024) void binscan_kernel(const int* __restrict__ bin_cnt,
                                                       int* __restrict__ bin_base,
                                                       int* __restrict__ bin_cursor) {
    __shared__ int s[1024];
    const int t = threadIdx.x;
    const int v = (t < NBINS) ? bin_cnt[t] : 0;
    s[t] = v;
    __syncthreads();
    #pragma unroll
    for (int off = 1; off < 1024; off <<= 1) {
        const int u = (t >= off) ? s[t - off] : 0;
        __syncthreads();
        s[t] += u;
        __syncthreads();
    }
    if (t < NBINS) {
        const int ex = s[t] - v;
        bin_base[t] = ex;
        bin_cursor[t] = ex;
    }
    if (t == 0) bin_base[NBINS] = E_TOT;
}

// ---------------------------------------------------------------------------
// Binned scatter (R4 winner): per-block LDS bin counts, one global run
// reservation per (block,bin), stores at run_base + local_pos (block-local
// contiguous runs -> lines assemble in one XCD's L2).
// payload.x = col_eff (18b) | row_low (7b) << 18 ; payload.y = val bits
// ---------------------------------------------------------------------------
__global__ __launch_bounds__(256) void binscatter_kernel(const int* __restrict__ rows,
                                                         const int* __restrict__ cols,
                                                         const float* __restrict__ vals,
                                                         int* __restrict__ bin_cursor,
                                                         u32x2* __restrict__ edata) {
    __shared__ int lcnt[NBINS];
    __shared__ int lbase[NBINS];
    const int t = threadIdx.x;
    for (int i = t; i < NBINS; i += 256) lcnt[i] = 0;
    __syncthreads();

    const int base = blockIdx.x * SC_CHUNK;
    int bin[SC_EPT], lpos[SC_EPT];
    u32x2 pay[SC_EPT];
    #pragma unroll
    for (int j = 0; j < SC_EPT; j++) {
        const int i = base + j * 256 + t;
        if (i < E_TOT) {
            const int r = __builtin_nontemporal_load(rows + i);
            const int c = __builtin_nontemporal_load(cols + i);
            const float v = __builtin_nontemporal_load(vals + i);
            const int b = r >> BSHIFT;
            bin[j] = b;
            lpos[j] = atomicAdd(&lcnt[b], 1);
            pay[j].x = (u32)(c + ((i >= N_EDGES) ? N_NODES : 0)) |
                       ((u32)(r & (BIN_ROWS - 1)) << 18);
            pay[j].y = __float_as_uint(v);
        } else {
            bin[j] = -1;
        }
    }
    __syncthreads();
    for (int b = t; b < NBINS; b += 256) {
        const int c = lcnt[b];
        if (c) lbase[b] = atomicAdd(&bin_cursor[b], c);
    }
    __syncthreads();
    #pragma unroll
    for (int j = 0; j < SC_EPT; j++) {
        if (bin[j] >= 0) edata[lbase[bin[j]] + lpos[j]] = pay[j];
    }
}

// ---------------------------------------------------------------------------
// Bin sort: one block per bin. Sorts the bin's edges into row order within
// the bin's contiguous edata2 range, and emits per-row CSR offsets.
// All reads/writes stay in a ~32 KB window per block -> L2-local.
// ---------------------------------------------------------------------------
__global__ __launch_bounds__(256) void binsort_kernel(const u32x2* __restrict__ edata,
                                                      u32x2* __restrict__ edata2,
                                                      const int* __restrict__ bin_base,
                                                      int* __restrict__ row_start) {
    __shared__ int rcnt[BIN_ROWS];
    __shared__ int rscan[BIN_ROWS];
    const int t = threadIdx.x;
    const int b = blockIdx.x;
    const int beg = bin_base[b];
    const int end = bin_base[b + 1];

    if (t < BIN_ROWS) rcnt[t] = 0;
    __syncthreads();
    for (int e = beg + t; e < end; e += 256)
        atomicAdd(&rcnt[edata[e].x >> 18], 1);
    __syncthreads();

    const int v = (t < BIN_ROWS) ? rcnt[t] : 0;
    if (t < BIN_ROWS) rscan[t] = v;
    __syncthreads();
    #pragma unroll
    for (int off = 1; off < BIN_ROWS; off <<= 1) {
        const int u = (t < BIN_ROWS && t >= off) ? rscan[t - off] : 0;
        __syncthreads();
        if (t < BIN_ROWS) rscan[t] += u;
        __syncthreads();
    }
    if (t < BIN_ROWS) {
        const int ex = rscan[t] - v;        // exclusive prefix
        rcnt[t] = ex;                       // reuse as cursor
        const int row = b * BIN_ROWS + t;
        if (row < N_NODES) row_start[row] = beg + ex;
    }
    __syncthreads();
    for (int e = beg + t; e < end; e += 256) {
        const u32x2 d = edata[e];
        const int pos = beg + atomicAdd(&rcnt[d.x >> 18], 1);
        u32x2 o;
        o.x = d.x & 0x3FFFFu;
        o.y = d.y;
        edata2[pos] = o;
    }
    if (b == NBINS - 1 && t == 0) row_start[N_NODES] = E_TOT;
}

// ---------------------------------------------------------------------------
// Gather-accumulate (no atomics): one wave per row, lane l owns features
// 2l, 2l+1 (one packed bf16x2 u32 per edge). Fused bias + ReLU.
// ---------------------------------------------------------------------------
__global__ __launch_bounds__(256) void gather_kernel(const u32* __restrict__ pre,
                                                     const u32x2* __restrict__ edata2,
                                                     const int* __restrict__ row_start,
                                                     const float* __restrict__ bias,
                                                     float* __restrict__ out) {
    const int lane = threadIdx.x & 63;
    const int wid = threadIdx.x >> 6;
    const int row = blockIdx.x * 4 + wid;
    if (row >= N_NODES) return;

    const int beg = row_start[row];
    const int end = row_start[row + 1];

    float ax = 0.f, ay = 0.f;
    int e = beg;
    for (; e + 4 <= end; e += 4) {
        const u32x2 d0 = __builtin_nontemporal_load(edata2 + e);
        const u32x2 d1 = __builtin_nontemporal_load(edata2 + e + 1);
        const u32x2 d2 = __builtin_nontemporal_load(edata2 + e + 2);
        const u32x2 d3 = __builtin_nontemporal_load(edata2 + e + 3);
        const u32 u0 = pre[(size_t)d0.x * 64 + lane];
        const u32 u1 = pre[(size_t)d1.x * 64 + lane];
        const u32 u2 = pre[(size_t)d2.x * 64 + lane];
        const u32 u3 = pre[(size_t)d3.x * 64 + lane];
        const float v0 = __uint_as_float(d0.y);
        const float v1 = __uint_as_float(d1.y);
        const float v2 = __uint_as_float(d2.y);
        const float v3 = __uint_as_float(d3.y);
        ax = fmaf(v0, __uint_as_float(u0 << 16), ax);
        ay = fmaf(v0, __uint_as_float(u0 & 0xFFFF0000u), ay);
        ax = fmaf(v1, __uint_as_float(u1 << 16), ax);
        ay = fmaf(v1, __uint_as_float(u1 & 0xFFFF0000u), ay);
        ax = fmaf(v2, __uint_as_float(u2 << 16), ax);
        ay = fmaf(v2, __uint_as_float(u2 & 0xFFFF0000u), ay);
        ax = fmaf(v3, __uint_as_float(u3 << 16), ax);
        ay = fmaf(v3, __uint_as_float(u3 & 0xFFFF0000u), ay);
    }
    for (; e < end; e++) {
        const u32x2 d = __builtin_nontemporal_load(edata2 + e);
        const u32 u = pre[(size_t)d.x * 64 + lane];
        const float v = __uint_as_float(d.y);
        ax = fmaf(v, __uint_as_float(u << 16), ax);
        ay = fmaf(v, __uint_as_float(u & 0xFFFF0000u), ay);
    }

    const float2 b = *(const float2*)(bias + lane * 2);
    f32x2 r;
    r.x = fmaxf(ax + b.x, 0.f);
    r.y = fmaxf(ay + b.y, 0.f);
    __builtin_nontemporal_store(r, (f32x2*)(out + (size_t)row * DOUT + lane * 2));
}

extern "C" void kernel_launch(void* const* d_in, const int* in_sizes, int n_in,
                              void* d_out, int out_size, void* d_ws, size_t ws_size,
                              hipStream_t stream) {
    (void)in_sizes; (void)n_in; (void)out_size; (void)ws_size;
    const float* x        = (const float*)d_in[0];   // [N, 128]
    const float* w        = (const float*)d_in[1];   // [2, 128, 128]
    const float* bias     = (const float*)d_in[2];   // [128]
    const float* sup_vals = (const float*)d_in[3];   // [2, E] flat
    const int*   sup_rows = (const int*)d_in[4];     // [2, E] flat
    const int*   sup_cols = (const int*)d_in[5];     // [2, E] flat
    float* out = (float*)d_out;                      // [N, 128]

    // ws layout
    char* ws = (char*)d_ws;
    u32*   pre       = (u32*)ws;                                        // 51.2 MB
    u32x2* edata     = (u32x2*)(ws + (size_t)N_SUP * N_NODES * 64 * 4); // 25.6 MB
    u32x2* edata2    = (u32x2*)((char*)edata + (size_t)E_TOT * 8);      // 25.6 MB
    int*   bin_cnt   = (int*)((char*)edata2 + (size_t)E_TOT * 8);
    int*   bin_base  = bin_cnt + NBINS;              // NBINS+1
    int*   bin_cursor= bin_base + NBINS + 1;
    int*   row_start = bin_cursor + NBINS;           // N+1

    // 1. GEMM -> bf16 pre
    {
        dim3 grid((N_NODES + 127) / 128, N_SUP);
        gemm_kernel<<<grid, 256, 0, stream>>>(x, w, pre);
    }
    // 2. bin CSR build + per-bin row sort
    (void)hipMemsetAsync(bin_cnt, 0, NBINS * sizeof(int), stream);
    binhist_kernel<<<NBLK_SC, 256, 0, stream>>>(sup_rows, bin_cnt);
    binscan_kernel<<<1, 1024, 0, stream>>>(bin_cnt, bin_base, bin_cursor);
    binscatter_kernel<<<NBLK_SC, 256, 0, stream>>>(sup_rows, sup_cols, sup_vals,
                                                   bin_cursor, edata);
    binsort_kernel<<<NBINS, 256, 0, stream>>>(edata, edata2, bin_base, row_start);
    // 3. row gather + bias + ReLU (no atomics)
    gather_kernel<<<(N_NODES + 3) / 4, 256, 0, stream>>>(pre, edata2, row_start, bias, out);
}

// Round 7
// 469.512 us; speedup vs baseline: 6.4179x; 1.1669x over previous
//
#include <hip/hip_runtime.h>

#define N_NODES 100000
#define N_EDGES 1600000
#define DIN 128
#define DOUT 128
#define N_SUP 2
#define E_TOT (N_SUP * N_EDGES)          // 3,200,000

#define BIN_ROWS 128
#define BSHIFT 7
#define NBINS ((N_NODES + BIN_ROWS - 1) / BIN_ROWS)    // 782

#define SC_EPT 16
#define SC_BLOCK 256
#define SC_CHUNK (SC_EPT * SC_BLOCK)                    // 4096
#define NBLK_SC ((E_TOT + SC_CHUNK - 1) / SC_CHUNK)     // 782

#define GEMM_ROWS 128
#define LDK 136      // padded LDS k-stride in bf16 units (odd multiple of 8)

typedef float        f32x2 __attribute__((ext_vector_type(2)));
typedef float        f32x4 __attribute__((ext_vector_type(4)));
typedef unsigned int u32;
typedef u32          u32x2 __attribute__((ext_vector_type(2)));
typedef u32          u32x4 __attribute__((ext_vector_type(4)));
typedef short        bf16x8 __attribute__((ext_vector_type(8)));

// round-to-nearest-even fp32 -> bf16 pair packed in one u32 (lo = even idx)
static __device__ __forceinline__ u32 pack_bf16x2(float lo, float hi) {
    u32 ul = __float_as_uint(lo);
    u32 uh = __float_as_uint(hi);
    ul = (ul + 0x7FFFu + ((ul >> 16) & 1u)) >> 16;
    uh = ((uh + 0x7FFFu + ((uh >> 16) & 1u)) >> 16) << 16;
    return ul | uh;
}

// ---------------------------------------------------------------------------
// x -> packed bf16 [node][64 u32]
// ---------------------------------------------------------------------------
__global__ __launch_bounds__(256) void xconv_kernel(const float* __restrict__ x,
                                                    u32* __restrict__ xb) {
    const int idx = blockIdx.x * 256 + threadIdx.x;   // 8 floats per thread
    const int total = N_NODES * 64 / 4;               // 1.6M
    if (idx < total) {
        const float* p = x + (size_t)idx * 8;
        const f32x4 a = __builtin_nontemporal_load((const f32x4*)p);
        const f32x4 b = __builtin_nontemporal_load((const f32x4*)(p + 4));
        u32x4 o;
        o.x = pack_bf16x2(a.x, a.y);
        o.y = pack_bf16x2(a.z, a.w);
        o.z = pack_bf16x2(b.x, b.y);
        o.w = pack_bf16x2(b.z, b.w);
        __builtin_nontemporal_store(o, (u32x4*)(xb + (size_t)idx * 4));
    }
}

// ---------------------------------------------------------------------------
// w[s][k][n] fp32 -> wT[s][n][k] packed bf16 (k-pairs in u32, lo = even k)
// ---------------------------------------------------------------------------
__global__ __launch_bounds__(256) void wconv_kernel(const float* __restrict__ w,
                                                    u32* __restrict__ wTb) {
    const int s = blockIdx.x;
    const int n = threadIdx.x >> 1;
    const int kh = (threadIdx.x & 1) * 64;
    const float* wp = w + (size_t)s * DIN * DOUT + n;
    u32 o[32];
    #pragma unroll
    for (int j = 0; j < 32; j++) {
        const float lo = wp[(size_t)(kh + 2 * j) * DOUT];
        const float hi = wp[(size_t)(kh + 2 * j + 1) * DOUT];
        o[j] = pack_bf16x2(lo, hi);
    }
    u32* op = wTb + ((size_t)s * 128 + n) * 64 + kh / 2;
    #pragma unroll
    for (int j = 0; j < 8; j++)
        *(u32x4*)(op + j * 4) = *(u32x4*)&o[j * 4];
}

// ---------------------------------------------------------------------------
// MFMA GEMM: pre[s] = x @ w[s] in bf16 (16x16x32 MFMA, fp32 accumulate).
// Block: 128 rows x 128 cols, 4 waves; wave = 2 m-tiles x 8 n-tiles.
// LDS: xs[128][LDK] + ws[128][LDK] bf16 (69.6 KB, 2 blocks/CU); epilogue
// re-uses the same LDS as a 128x129 fp32 transpose buffer.
// ---------------------------------------------------------------------------
__global__ __launch_bounds__(256) void mfma_gemm_kernel(const u32* __restrict__ xb,
                                                        const u32* __restrict__ wTb,
                                                        u32* __restrict__ pre) {
    __shared__ alignas(16) unsigned short stage[2][GEMM_ROWS][LDK];  // 69,632 B
    float (*epi)[129] = (float (*)[129])(void*)stage;                // 66,048 B

    const int s = blockIdx.y;
    const int row0 = blockIdx.x * GEMM_ROWS;
    const int t = threadIdx.x;
    const int lane = t & 63;
    const int wv = t >> 6;

    // stage x tile (rows row0..row0+127), packed u32 k-pairs -> bf16 LDS rows
    {
        const int r = t >> 1;
        const int half = t & 1;               // k 0..63 / 64..127
        const int gr = row0 + r;
        u32* dst = (u32*)&stage[0][r][half * 64];
        if (gr < N_NODES) {
            const u32* p = xb + (size_t)gr * 64 + half * 32;
            #pragma unroll
            for (int j = 0; j < 8; j++)
                *(u32x4*)(dst + j * 4) = *(const u32x4*)(p + j * 4);
        } else {
            #pragma unroll
            for (int j = 0; j < 8; j++)
                *(u32x4*)(dst + j * 4) = (u32x4){0, 0, 0, 0};
        }
        // stage wT[s] (128 n-rows x 128 k)
        const u32* wp = wTb + ((size_t)s * 128 + r) * 64 + half * 32;
        u32* wdst = (u32*)&stage[1][r][half * 64];
        #pragma unroll
        for (int j = 0; j < 8; j++)
            *(u32x4*)(wdst + j * 4) = *(const u32x4*)(wp + j * 4);
    }
    __syncthreads();

    const int q = lane >> 4;       // quad: k sub-block
    const int ml = lane & 15;      // row within m-tile / col within n-tile
    const int m0 = wv * 32;

    f32x4 acc[2][8];
    #pragma unroll
    for (int mt = 0; mt < 2; mt++)
        #pragma unroll
        for (int nt = 0; nt < 8; nt++) acc[mt][nt] = (f32x4){0.f, 0.f, 0.f, 0.f};

    #pragma unroll
    for (int kt = 0; kt < 4; kt++) {
        const int k0 = kt * 32 + q * 8;
        const bf16x8 a0 = *(const bf16x8*)&stage[0][m0 + ml][k0];
        const bf16x8 a1 = *(const bf16x8*)&stage[0][m0 + 16 + ml][k0];
        #pragma unroll
        for (int nt = 0; nt < 8; nt++) {
            const bf16x8 b = *(const bf16x8*)&stage[1][nt * 16 + ml][k0];
            acc[0][nt] = __builtin_amdgcn_mfma_f32_16x16x32_bf16(a0, b, acc[0][nt], 0, 0, 0);
            acc[1][nt] = __builtin_amdgcn_mfma_f32_16x16x32_bf16(a1, b, acc[1][nt], 0, 0, 0);
        }
    }
    __syncthreads();   // done reading stage; epi aliases it

    // C-layout (col=lane&15, row=quad*4+reg) -> LDS fp32 [row][feat]
    #pragma unroll
    for (int mt = 0; mt < 2; mt++)
        #pragma unroll
        for (int nt = 0; nt < 8; nt++)
            #pragma unroll
            for (int r = 0; r < 4; r++)
                epi[m0 + mt * 16 + q * 4 + r][nt * 16 + ml] = acc[mt][nt][r];
    __syncthreads();

    // packed bf16-pair store, coalesced
    {
        const int row = t >> 1;
        const int half = t & 1;
        const int gr = row0 + row;
        if (gr < N_NODES) {
            u32 ov[32];
            #pragma unroll
            for (int j = 0; j < 32; j++)
                ov[j] = pack_bf16x2(epi[row][half * 64 + 2 * j],
                                    epi[row][half * 64 + 2 * j + 1]);
            u32* op = pre + ((size_t)s * N_NODES + gr) * 64 + half * 32;
            #pragma unroll
            for (int j = 0; j < 8; j++)
                __builtin_nontemporal_store(*(u32x4*)&ov[j * 4], (u32x4*)(op + j * 4));
        }
    }
}

// ---------------------------------------------------------------------------
// Bin histogram: LDS hist per block, one global atomic per (block, bin)
// ---------------------------------------------------------------------------
__global__ __launch_bounds__(256) void binhist_kernel(const int* __restrict__ rows,
                                                      int* __restrict__ bin_cnt) {
    __shared__ int h[NBINS];
    const int t = threadIdx.x;
    for (int i = t; i < NBINS; i += 256) h[i] = 0;
    __syncthreads();
    const int base = blockIdx.x * SC_CHUNK;
    #pragma unroll
    for (int j = 0; j < SC_EPT; j++) {
        const int i = base + j * 256 + t;
        if (i < E_TOT) atomicAdd(&h[__builtin_nontemporal_load(rows + i) >> BSHIFT], 1);
    }
    __syncthreads();
    for (int i = t; i < NBINS; i += 256)
        if (h[i]) atomicAdd(&bin_cnt[i], h[i]);
}

// ---------------------------------------------------------------------------
// Exclusive scan over NBINS (single block)
// ---------------------------------------------------------------------------
__global__ __launch_bounds__(1024) void binscan_kernel(const int* __restrict__ bin_cnt,
                                                       int* __restrict__ bin_base,
                                                       int* __restrict__ bin_cursor) {
    __shared__ int s[1024];
    const int t = threadIdx.x;
    const int v = (t < NBINS) ? bin_cnt[t] : 0;
    s[t] = v;
    __syncthreads();
    #pragma unroll
    for (int off = 1; off < 1024; off <<= 1) {
        const int u = (t >= off) ? s[t - off] : 0;
        __syncthreads();
        s[t] += u;
        __syncthreads();
    }
    if (t < NBINS) {
        const int ex = s[t] - v;
        bin_base[t] = ex;
        bin_cursor[t] = ex;
    }
    if (t == 0) bin_base[NBINS] = E_TOT;
}

// ---------------------------------------------------------------------------
// Binned scatter: per-block LDS bin counts, one global run reservation per
// (block,bin), stores at run_base + local_pos (block-local contiguous runs).
// payload.x = col_eff (18b) | row_low (7b) << 18 ; payload.y = val bits
// ---------------------------------------------------------------------------
__global__ __launch_bounds__(256) void binscatter_kernel(const int* __restrict__ rows,
                                                         const int* __restrict__ cols,
                                                         const float* __restrict__ vals,
                                                         int* __restrict__ bin_cursor,
                                                         u32x2* __restrict__ edata) {
    __shared__ int lcnt[NBINS];
    __shared__ int lbase[NBINS];
    const int t = threadIdx.x;
    for (int i = t; i < NBINS; i += 256) lcnt[i] = 0;
    __syncthreads();

    const int base = blockIdx.x * SC_CHUNK;
    int bin[SC_EPT], lpos[SC_EPT];
    u32x2 pay[SC_EPT];
    #pragma unroll
    for (int j = 0; j < SC_EPT; j++) {
        const int i = base + j * 256 + t;
        if (i < E_TOT) {
            const int r = __builtin_nontemporal_load(rows + i);
            const int c = __builtin_nontemporal_load(cols + i);
            const float v = __builtin_nontemporal_load(vals + i);
            const int b = r >> BSHIFT;
            bin[j] = b;
            lpos[j] = atomicAdd(&lcnt[b], 1);
            pay[j].x = (u32)(c + ((i >= N_EDGES) ? N_NODES : 0)) |
                       ((u32)(r & (BIN_ROWS - 1)) << 18);
            pay[j].y = __float_as_uint(v);
        } else {
            bin[j] = -1;
        }
    }
    __syncthreads();
    for (int b = t; b < NBINS; b += 256) {
        const int c = lcnt[b];
        if (c) lbase[b] = atomicAdd(&bin_cursor[b], c);
    }
    __syncthreads();
    #pragma unroll
    for (int j = 0; j < SC_EPT; j++) {
        if (bin[j] >= 0) edata[lbase[bin[j]] + lpos[j]] = pay[j];
    }
}

// ---------------------------------------------------------------------------
// Bin sort: one block per bin; row-sorts the bin's edges into edata2 and
// emits per-row CSR offsets. All traffic stays in a ~32 KB L2-local window.
// ---------------------------------------------------------------------------
__global__ __launch_bounds__(256) void binsort_kernel(const u32x2* __restrict__ edata,
                                                      u32x2* __restrict__ edata2,
                                                      const int* __restrict__ bin_base,
                                                      int* __restrict__ row_start) {
    __shared__ int rcnt[BIN_ROWS];
    __shared__ int rscan[BIN_ROWS];
    const int t = threadIdx.x;
    const int b = blockIdx.x;
    const int beg = bin_base[b];
    const int end = bin_base[b + 1];

    if (t < BIN_ROWS) rcnt[t] = 0;
    __syncthreads();
    for (int e = beg + t; e < end; e += 256)
        atomicAdd(&rcnt[edata[e].x >> 18], 1);
    __syncthreads();

    const int v = (t < BIN_ROWS) ? rcnt[t] : 0;
    if (t < BIN_ROWS) rscan[t] = v;
    __syncthreads();
    #pragma unroll
    for (int off = 1; off < BIN_ROWS; off <<= 1) {
        const int u = (t < BIN_ROWS && t >= off) ? rscan[t - off] : 0;
        __syncthreads();
        if (t < BIN_ROWS) rscan[t] += u;
        __syncthreads();
    }
    if (t < BIN_ROWS) {
        const int ex = rscan[t] - v;
        rcnt[t] = ex;                       // reuse as cursor
        const int row = b * BIN_ROWS + t;
        if (row < N_NODES) row_start[row] = beg + ex;
    }
    __syncthreads();
    for (int e = beg + t; e < end; e += 256) {
        const u32x2 d = edata[e];
        const int pos = beg + atomicAdd(&rcnt[d.x >> 18], 1);
        u32x2 o;
        o.x = d.x & 0x3FFFFu;
        o.y = d.y;
        edata2[pos] = o;
    }
    if (b == NBINS - 1 && t == 0) row_start[N_NODES] = E_TOT;
}

// ---------------------------------------------------------------------------
// Gather-accumulate (no atomics): one wave per row, lane l owns features
// 2l, 2l+1 (one packed bf16x2 u32 per edge). Fused bias + ReLU.
// ---------------------------------------------------------------------------
__global__ __launch_bounds__(256) void gather_kernel(const u32* __restrict__ pre,
                                                     const u32x2* __restrict__ edata2,
                                                     const int* __restrict__ row_start,
                                                     const float* __restrict__ bias,
                                                     float* __restrict__ out) {
    const int lane = threadIdx.x & 63;
    const int wid = threadIdx.x >> 6;
    const int row = blockIdx.x * 4 + wid;
    if (row >= N_NODES) return;

    const int beg = row_start[row];
    const int end = row_start[row + 1];

    float ax = 0.f, ay = 0.f;
    int e = beg;
    for (; e + 4 <= end; e += 4) {
        const u32x2 d0 = __builtin_nontemporal_load(edata2 + e);
        const u32x2 d1 = __builtin_nontemporal_load(edata2 + e + 1);
        const u32x2 d2 = __builtin_nontemporal_load(edata2 + e + 2);
        const u32x2 d3 = __builtin_nontemporal_load(edata2 + e + 3);
        const u32 u0 = pre[(size_t)d0.x * 64 + lane];
        const u32 u1 = pre[(size_t)d1.x * 64 + lane];
        const u32 u2 = pre[(size_t)d2.x * 64 + lane];
        const u32 u3 = pre[(size_t)d3.x * 64 + lane];
        const float v0 = __uint_as_float(d0.y);
        const float v1 = __uint_as_float(d1.y);
        const float v2 = __uint_as_float(d2.y);
        const float v3 = __uint_as_float(d3.y);
        ax = fmaf(v0, __uint_as_float(u0 << 16), ax);
        ay = fmaf(v0, __uint_as_float(u0 & 0xFFFF0000u), ay);
        ax = fmaf(v1, __uint_as_float(u1 << 16), ax);
        ay = fmaf(v1, __uint_as_float(u1 & 0xFFFF0000u), ay);
        ax = fmaf(v2, __uint_as_float(u2 << 16), ax);
        ay = fmaf(v2, __uint_as_float(u2 & 0xFFFF0000u), ay);
        ax = fmaf(v3, __uint_as_float(u3 << 16), ax);
        ay = fmaf(v3, __uint_as_float(u3 & 0xFFFF0000u), ay);
    }
    for (; e < end; e++) {
        const u32x2 d = __builtin_nontemporal_load(edata2 + e);
        const u32 u = pre[(size_t)d.x * 64 + lane];
        const float v = __uint_as_float(d.y);
        ax = fmaf(v, __uint_as_float(u << 16), ax);
        ay = fmaf(v, __uint_as_float(u & 0xFFFF0000u), ay);
    }

    const float2 b = *(const float2*)(bias + lane * 2);
    f32x2 r;
    r.x = fmaxf(ax + b.x, 0.f);
    r.y = fmaxf(ay + b.y, 0.f);
    __builtin_nontemporal_store(r, (f32x2*)(out + (size_t)row * DOUT + lane * 2));
}

extern "C" void kernel_launch(void* const* d_in, const int* in_sizes, int n_in,
                              void* d_out, int out_size, void* d_ws, size_t ws_size,
                              hipStream_t stream) {
    (void)in_sizes; (void)n_in; (void)out_size; (void)ws_size;
    const float* x        = (const float*)d_in[0];   // [N, 128]
    const float* w        = (const float*)d_in[1];   // [2, 128, 128]
    const float* bias     = (const float*)d_in[2];   // [128]
    const float* sup_vals = (const float*)d_in[3];   // [2, E] flat
    const int*   sup_rows = (const int*)d_in[4];     // [2, E] flat
    const int*   sup_cols = (const int*)d_in[5];     // [2, E] flat
    float* out = (float*)d_out;                      // [N, 128]

    // ws layout
    char* ws = (char*)d_ws;
    u32*   pre       = (u32*)ws;                                        // 51.2 MB
    u32x2* edata     = (u32x2*)(ws + (size_t)N_SUP * N_NODES * 64 * 4); // 25.6 MB
    u32x2* edata2    = (u32x2*)((char*)edata + (size_t)E_TOT * 8);      // 25.6 MB
    u32*   xb        = (u32*)edata2;   // aliases edata2: xb dead before binsort writes
    int*   bin_cnt   = (int*)((char*)edata2 + (size_t)E_TOT * 8);
    int*   bin_base  = bin_cnt + NBINS;              // NBINS+1
    int*   bin_cursor= bin_base + NBINS + 1;
    int*   row_start = bin_cursor + NBINS;           // N+1
    u32*   wTb       = (u32*)(row_start + N_NODES + 1);   // 64 KB

    // 1. convert x -> bf16, w -> transposed bf16
    xconv_kernel<<<(N_NODES * 64 / 4 + 255) / 256, 256, 0, stream>>>(x, xb);
    wconv_kernel<<<N_SUP, 256, 0, stream>>>(w, wTb);
    // 2. MFMA GEMM -> bf16 pre
    {
        dim3 grid((N_NODES + GEMM_ROWS - 1) / GEMM_ROWS, N_SUP);
        mfma_gemm_kernel<<<grid, 256, 0, stream>>>(xb, wTb, pre);
    }
    // 3. bin CSR build + per-bin row sort
    (void)hipMemsetAsync(bin_cnt, 0, NBINS * sizeof(int), stream);
    binhist_kernel<<<NBLK_SC, 256, 0, stream>>>(sup_rows, bin_cnt);
    binscan_kernel<<<1, 1024, 0, stream>>>(bin_cnt, bin_base, bin_cursor);
    binscatter_kernel<<<NBLK_SC, 256, 0, stream>>>(sup_rows, sup_cols, sup_vals,
                                                   bin_cursor, edata);
    binsort_kernel<<<NBINS, 256, 0, stream>>>(edata, edata2, bin_base, row_start);
    // 4. row gather + bias + ReLU (no atomics)
    gather_kernel<<<(N_NODES + 3) / 4, 256, 0, stream>>>(pre, edata2, row_start, bias, out);
}